// Round 9
// baseline (428.354 us; speedup 1.0000x reference)
//
#include <hip/hip_runtime.h>
#include <hip/hip_bf16.h>

typedef __hip_bfloat16 bf16;
typedef __attribute__((ext_vector_type(8))) short s8v;   // 8 bf16 = 4 VGPRs (MFMA A/B frag)
typedef __attribute__((ext_vector_type(4))) float f4v;   // MFMA C/D frag

#define B_  2
#define S_  2048
#define D_  2048
#define H_  16
#define HD_ 128
#define INV_NORM 0.08838834764831845f

static __device__ __forceinline__ f4v mfma16(s8v a, s8v b, f4v c) {
    return __builtin_amdgcn_mfma_f32_16x16x32_bf16(a, b, c, 0, 0, 0);
}

static __device__ __forceinline__ void gload_lds(const void* gp, void* lp) {
    __builtin_amdgcn_global_load_lds(
        (const __attribute__((address_space(1))) unsigned int*)gp,
        (__attribute__((address_space(3))) unsigned int*)lp, 16, 0, 0);
}

// fp32 -> bf16 elementwise convert, 4 elems/thread
__global__ __launch_bounds__(256)
void cvt_f32_bf16(const float* __restrict__ src, bf16* __restrict__ dst, int n4)
{
    int i = blockIdx.x * 256 + threadIdx.x;
    if (i < n4) {
        float4 f = ((const float4*)src)[i];
        union { ushort4 u4; bf16 h[4]; } p;
        p.h[0] = __float2bfloat16(f.x);
        p.h[1] = __float2bfloat16(f.y);
        p.h[2] = __float2bfloat16(f.z);
        p.h[3] = __float2bfloat16(f.w);
        ((ushort4*)dst)[i] = p.u4;
    }
}

#define VMW(s) asm volatile("s_waitcnt " s ::: "memory")
#define BARR() { __builtin_amdgcn_s_barrier(); asm volatile("" ::: "memory"); }

// ---------------------------------------------------------------------------
// R9: gemm_qkv9 — QKV GEMM retiled 256M x 192N to kill grid quantization.
// R8 post-mortem: qkv8 (384 blocks, 1/CU) = 1.5 rounds -> 75% residency;
// three schedule variants (R5/R6/R7) all ~116-125 µs -> scheduling exhausted,
// quantization is the remaining lever. New grid: 16 bm x 32 bn = 512 equal
// blocks = EXACTLY 2 full rounds of 256 CUs (100% balance).
//
// Structure = dense8-proven 2-phase sync + qkv8 counted-vmcnt ledger:
//   8 waves (wr=wave>>2: 2 M-halves; wc=wave&3: 4 N-quarters of 48 cols).
//   Wave tile 128M x 48N; acc[8][3] (96 VGPR). BK=64.
//   LDS/buffer: A-lo 16K @0, A-hi 16K @16K, B 24K @32K = 56K; x2 = 112 KB.
//   ph0: read a0(A-lo,8)+bfr(B,6) -> 24 MFMA (mi0-3 x nj0-2 x ks0-1).
//   ph1: read a1(A-hi,8), B in regs -> 24 MFMA (mi4-7).
// vmcnt ledger (FIFO/wave; A chunks 2 loads, B 3): prologue t0{A-lo,B,A-hi}
//   + t1{A-lo,B} = 12 outstanding. Entry: vmcnt(5) retires exactly this
//   tile's 7 (oldest). ph0 stages (t+1,A-hi) +2; ph1 stages (t+2,A-lo)+
//   (t+2,B) +5 -> 12 invariant. Tails: kt=30 P2=0; kt=31 vmcnt(0).
// Race audit (= dense8's, passed): (t+1,A-hi) -> buf^1, its last reads were
//   tile t-1 ph1 (drained pre-MFMA) and entry barrier precedes issue.
//   (t+2,A-lo/B) -> current buf; those chunks' reads are all in ph0, drained
//   before ph0's MFMAs, and the ph0-close barrier precedes the ph1 issue.
//   ph1's reads (A-hi) don't overlap ph1's DMA (A-lo,B). 2 barriers/tile.
// Swizzle: all LDS row bases (wc*48, nj*16, mi*32, wr*16) are multiples of
//   8 -> row&7 == col&7 preserved; same pre-swizzled source / sx read terms.
// ---------------------------------------------------------------------------
#define QSTAGE2(gptr, t, choff)                                                 \
  { const size_t co = (size_t)(t) * 64;                                         \
    gload_lds(gptr + co + srcO0, lds + ((t) & 1) * 57344 + (choff) + dst0);     \
    gload_lds(gptr + co + srcO1, lds + ((t) & 1) * 57344 + (choff) + dst1); }
#define QSTAGE3(gptr, t, choff)                                                 \
  { const size_t co = (size_t)(t) * 64;                                         \
    gload_lds(gptr + co + srcO0, lds + ((t) & 1) * 57344 + (choff) + dst0);     \
    gload_lds(gptr + co + srcO1, lds + ((t) & 1) * 57344 + (choff) + dst1);     \
    gload_lds(gptr + co + srcO2, lds + ((t) & 1) * 57344 + (choff) + dst2); }

#define QKTILE(P1, P2, VA)                                                      \
  {                                                                             \
    const int bufB = (kt & 1) * 57344;                                          \
    VMW(VA); BARR();                                                            \
    if (P1) QSTAGE2(gA2, kt + 1, 16384);                                        \
    _Pragma("unroll") for (int mi = 0; mi < 4; ++mi) {                          \
      a0[mi][0] = *(const s8v*)(lds + bufB + aR + mi * 4096 + sx0);             \
      a0[mi][1] = *(const s8v*)(lds + bufB + aR + mi * 4096 + sx1);             \
    }                                                                           \
    _Pragma("unroll") for (int nj = 0; nj < 3; ++nj) {                          \
      bfr[nj][0] = *(const s8v*)(lds + bufB + bR + nj * 2048 + sx0);            \
      bfr[nj][1] = *(const s8v*)(lds + bufB + bR + nj * 2048 + sx1);            \
    }                                                                           \
    __builtin_amdgcn_s_setprio(1);                                              \
    _Pragma("unroll") for (int mi = 0; mi < 4; ++mi)                            \
    _Pragma("unroll") for (int nj = 0; nj < 3; ++nj) {                          \
      acc[mi][nj] = mfma16(a0[mi][0], bfr[nj][0], acc[mi][nj]);                 \
      acc[mi][nj] = mfma16(a0[mi][1], bfr[nj][1], acc[mi][nj]);                 \
    }                                                                           \
    __builtin_amdgcn_s_setprio(0);                                              \
    BARR();                                                                     \
    if (P2) { QSTAGE2(gA, kt + 2, 0); QSTAGE3(gB, kt + 2, 32768); }             \
    _Pragma("unroll") for (int mi = 0; mi < 4; ++mi) {                          \
      a1[mi][0] = *(const s8v*)(lds + bufB + aR + (4 + mi) * 4096 + sx0);       \
      a1[mi][1] = *(const s8v*)(lds + bufB + aR + (4 + mi) * 4096 + sx1);       \
    }                                                                           \
    __builtin_amdgcn_s_setprio(1);                                              \
    _Pragma("unroll") for (int mi = 0; mi < 4; ++mi)                            \
    _Pragma("unroll") for (int nj = 0; nj < 3; ++nj) {                          \
      acc[4 + mi][nj] = mfma16(a1[mi][0], bfr[nj][0], acc[4 + mi][nj]);         \
      acc[4 + mi][nj] = mfma16(a1[mi][1], bfr[nj][1], acc[4 + mi][nj]);         \
    }                                                                           \
    __builtin_amdgcn_s_setprio(0);                                              \
  }

__global__ __launch_bounds__(512, 2)
void gemm_qkv9(const bf16* __restrict__ A, const bf16* __restrict__ Bw,
               const float* __restrict__ bias,
               bf16* __restrict__ o0, bf16* __restrict__ o1, bf16* __restrict__ o2)
{
    __shared__ __align__(16) char lds[114688];
    const int tid  = threadIdx.x;
    const int wave = tid >> 6, lane = tid & 63;
    const int col  = lane & 15, quad = lane >> 4;
    const int wr   = wave >> 2, wc = wave & 3;

    // XCD-chunked bijective block swizzle (nwg=512, 512%8==0):
    int id = (int)blockIdx.y * 32 + (int)blockIdx.x;
    id = (id & 7) * 64 + (id >> 3);
    const int bm = id >> 5, bn = id & 31;

    const bf16* gA  = A  + (size_t)bm * 256 * 2048;
    const bf16* gA2 = gA + (size_t)128 * 2048;
    const bf16* gB  = Bw + (size_t)bn * 192 * 2048;

    // staging: granule row r0=tid>>3, blk=tid&7; source pre-swizzled.
    const int r0   = tid >> 3, bk0 = tid & 7;
    const int srcO0 = r0 * 2048 + ((bk0 ^ (r0 & 7)) << 3);
    const int srcO1 = srcO0 + 64 * 2048;            // rows +64 (same row&7)
    const int srcO2 = srcO0 + 128 * 2048;           // rows +128 (B only)
    const int dst0 = tid * 16, dst1 = dst0 + 8192, dst2 = dst0 + 16384;

    // fragment-read addressing: row&7 == col&7 for every frag row
    const int sx0 = ((quad ^ (col & 7)) << 4);          // ks=0 swizzled k-blk
    const int sx1 = (((4 + quad) ^ (col & 7)) << 4);    // ks=1
    const int aR  = (wr * 16 + col) * 128;              // + mi*4096
    const int bR  = (wc * 48 + col) * 128 + 32768;      // + nj*2048

    const f4v fzero = {0.f, 0.f, 0.f, 0.f};
    f4v acc[8][3];
#pragma unroll
    for (int i = 0; i < 8; i++)
#pragma unroll
        for (int j = 0; j < 3; j++) acc[i][j] = fzero;
    s8v a0[4][2], a1[4][2], bfr[3][2];

    // prologue: t0 {A-lo, B, A-hi} + t1 {A-lo, B} = 12 loads (FIFO)
    QSTAGE2(gA,  0, 0);
    QSTAGE3(gB,  0, 32768);
    QSTAGE2(gA2, 0, 16384);
    QSTAGE2(gA,  1, 0);
    QSTAGE3(gB,  1, 32768);

    for (int kt = 0; kt < 30; ++kt) {
        QKTILE(1, 1, "vmcnt(5)");
    }
    {   const int kt = 30;              // t+2 = 32: nothing to stage at ph1
        QKTILE(1, 0, "vmcnt(5)");
    }
    {   const int kt = 31;              // tail: drain
        QKTILE(0, 0, "vmcnt(0)");
    }

    // epilogue: scatter to Q / K / V^T. c in [0,6144); 16-col segments never
    // straddle a 128-col (h,t) group (c0 is a multiple of 16).
#pragma unroll
    for (int mi = 0; mi < 8; ++mi) {
#pragma unroll
        for (int nj = 0; nj < 3; ++nj) {
            const int c  = bn * 192 + wc * 48 + nj * 16 + col;
            const int cg = c >> 7;                      // 128-col group id
            const int t3 = cg % 3, hh = cg / 3;
            const int hd = c & 127;
            const float bv = bias[c];
            const int r = bm * 256 + mi * 32 + wr * 16 + (quad << 2);
            const int bi = r >> 11, srow = r & (S_ - 1);
            if (t3 == 2) {
                union { ushort4 u4; bf16 hv[4]; } pk;
#pragma unroll
                for (int rg = 0; rg < 4; ++rg)
                    pk.hv[rg] = __float2bfloat16(acc[mi][nj][rg] + bv);
                *(ushort4*)(o2 + ((size_t)(bi * H_ + hh) * HD_ + hd) * S_ + srow) = pk.u4;
            } else {
                bf16* dst = (t3 == 0) ? o0 : o1;
#pragma unroll
                for (int rg = 0; rg < 4; ++rg)
                    dst[((size_t)(bi * H_ + hh) * S_ + (srow + rg)) * HD_ + hd] =
                        __float2bfloat16(acc[mi][nj][rg] + bv);
            }
        }
    }
}

// ---------------------------------------------------------------------------
// gemm_dense8 — unchanged from R8 (verified). out = ctx @ Wd^T + bias + resid.
// Tile 256Mx128N, grid 16x16 = 256 blocks = 1/CU. 2-phase counted-vmcnt.
// ---------------------------------------------------------------------------
#define STAGE_D(gptr, t, choff)                                                 \
  { const size_t co = (size_t)(t) * 64;                                         \
    gload_lds(gptr + co + srcO0, lds + ((t) & 1) * 49152 + (choff) + dst0);     \
    gload_lds(gptr + co + srcO1, lds + ((t) & 1) * 49152 + (choff) + dst1); }

#define DKTILE(P1, P2, VA)                                                      \
  {                                                                             \
    const int bufB = (kt & 1) * 49152;                                          \
    VMW(VA); BARR();                                                            \
    if (P1) STAGE_D(gA2, kt + 1, 16384);                                        \
    _Pragma("unroll") for (int mi = 0; mi < 2; ++mi) {                          \
      alo[mi][0] = *(const s8v*)(lds + bufB + aR + mi * 8192 + sx0);            \
      alo[mi][1] = *(const s8v*)(lds + bufB + aR + mi * 8192 + sx1);            \
    }                                                                           \
    _Pragma("unroll") for (int nj = 0; nj < 4; ++nj) {                          \
      bfr[nj][0] = *(const s8v*)(lds + bufB + bR + nj * 4096 + sx0);            \
      bfr[nj][1] = *(const s8v*)(lds + bufB + bR + nj * 4096 + sx1);            \
    }                                                                           \
    __builtin_amdgcn_s_setprio(1);                                              \
    _Pragma("unroll") for (int mi = 0; mi < 2; ++mi)                            \
    _Pragma("unroll") for (int nj = 0; nj < 4; ++nj) {                          \
      acc[mi][nj] = mfma16(alo[mi][0], bfr[nj][0], acc[mi][nj]);                \
      acc[mi][nj] = mfma16(alo[mi][1], bfr[nj][1], acc[mi][nj]);                \
    }                                                                           \
    __builtin_amdgcn_s_setprio(0);                                              \
    BARR();                                                                     \
    if (P2) { STAGE_D(gA, kt + 2, 0); STAGE_D(gB, kt + 2, 32768); }             \
    _Pragma("unroll") for (int mi = 0; mi < 2; ++mi) {                          \
      ahi[mi][0] = *(const s8v*)(lds + bufB + 16384 + aR + mi * 8192 + sx0);    \
      ahi[mi][1] = *(const s8v*)(lds + bufB + 16384 + aR + mi * 8192 + sx1);    \
    }                                                                           \
    __builtin_amdgcn_s_setprio(1);                                              \
    _Pragma("unroll") for (int mi = 0; mi < 2; ++mi)                            \
    _Pragma("unroll") for (int nj = 0; nj < 4; ++nj) {                          \
      acc[2 + mi][nj] = mfma16(ahi[mi][0], bfr[nj][0], acc[2 + mi][nj]);        \
      acc[2 + mi][nj] = mfma16(ahi[mi][1], bfr[nj][1], acc[2 + mi][nj]);        \
    }                                                                           \
    __builtin_amdgcn_s_setprio(0);                                              \
  }

__global__ __launch_bounds__(512, 2)
void gemm_dense8(const bf16* __restrict__ A, const bf16* __restrict__ Bw,
                 const float* __restrict__ bias, const float* __restrict__ resid,
                 float* __restrict__ of)
{
    __shared__ __align__(16) char lds[98304];
    const int tid  = threadIdx.x;
    const int wave = tid >> 6, lane = tid & 63;
    const int col  = lane & 15, quad = lane >> 4;
    const int wr   = wave >> 1, wc = wave & 1;

    // XCD-chunked bijective swizzle (nwg=256, 256%8==0):
    int id = (int)blockIdx.y * 16 + (int)blockIdx.x;
    id = (id & 7) * 32 + (id >> 3);
    const int bm = id >> 4, bn = id & 15;

    const bf16* gA  = A  + (size_t)bm * 256 * 2048;
    const bf16* gA2 = gA + (size_t)128 * 2048;
    const bf16* gB  = Bw + (size_t)bn * 128 * 2048;

    const int r0   = tid >> 3, bk0 = tid & 7;
    const int srcO0 = r0 * 2048 + ((bk0 ^ (r0 & 7)) << 3);
    const int srcO1 = srcO0 + 64 * 2048;
    const int dst0 = tid * 16, dst1 = dst0 + 8192;

    const int sx0 = ((quad ^ (col & 7)) << 4);
    const int sx1 = (((4 + quad) ^ (col & 7)) << 4);
    const int aR  = (wr * 16 + col) * 128;              // + mi*8192 (A-lo/A-hi)
    const int bR  = (wc * 16 + col) * 128 + 32768;      // + nj*4096

    const f4v fzero = {0.f, 0.f, 0.f, 0.f};
    f4v acc[4][4];
#pragma unroll
    for (int i = 0; i < 4; i++)
#pragma unroll
        for (int j = 0; j < 4; j++) acc[i][j] = fzero;
    s8v alo[2][2], ahi[2][2], bfr[4][2];

    // prologue: tile0 {A-lo, B, A-hi} + tile1 {A-lo, B} = 10 loads (FIFO)
    STAGE_D(gA,  0, 0);
    STAGE_D(gB,  0, 32768);
    STAGE_D(gA2, 0, 16384);
    STAGE_D(gA,  1, 0);
    STAGE_D(gB,  1, 32768);

    for (int kt = 0; kt < 30; ++kt) {
        DKTILE(1, 1, "vmcnt(4)");
    }
    {   const int kt = 30;              // t+2 = 32: nothing to stage at ph1
        DKTILE(1, 0, "vmcnt(4)");
    }
    {   const int kt = 31;              // tail: drain
        DKTILE(0, 0, "vmcnt(0)");
    }

    // epilogue: fp32 out with bias + residual
#pragma unroll
    for (int mi = 0; mi < 4; ++mi) {
#pragma unroll
        for (int nj = 0; nj < 4; ++nj) {
            const int c = bn * 128 + nj * 32 + wc * 16 + col;
            const float bv = bias[c];
            const int r = bm * 256 + mi * 64 + wr * 16 + (quad << 2);
#pragma unroll
            for (int rg = 0; rg < 4; ++rg) {
                const size_t idx = (size_t)(r + rg) * D_ + c;
                of[idx] = acc[mi][nj][rg] + bv + resid[idx];
            }
        }
    }
}

// Flash attention — unchanged from R2 (verified: spill-free, dbuf DMA).
__global__ __launch_bounds__(256, 2)
void attn(const bf16* __restrict__ Qb, const bf16* __restrict__ Kb,
          const bf16* __restrict__ Vt, bf16* __restrict__ ctx)
{
    __shared__ __align__(16) char Ksm[2][64 * 256];
    __shared__ __align__(16) char Vsm[2][128 * 128];
    __shared__ __align__(16) char Pl[4 * 16 * 128];

    const int x = blockIdx.x;
    const int bh = blockIdx.y;
    const int u = (bh >> 3) & 1;
    const int qb = u ? x : (int)gridDim.x - 1 - x;
    const int b = bh >> 4, h = bh & 15;
    const int tid = threadIdx.x;
    const int wave = tid >> 6, lane = tid & 63;
    const int col = lane & 15, quad = lane >> 4;
    const int q0 = qb << 6;
    const int qg = q0 + wave * 16 + col;
    const float slope = exp2f(-0.5f * (float)(h + 1));
    const int sw = (col & 7) << 4;

    const bf16* Qp = Qb + ((size_t)bh * S_ + q0 + wave * 16) * HD_;
    s8v aq[4];
#pragma unroll
    for (int c = 0; c < 4; c++)
        aq[c] = *(const s8v*)(Qp + (size_t)col * HD_ + c * 32 + quad * 8);

    const f4v fzero = {0.f, 0.f, 0.f, 0.f};
    f4v o[8];
#pragma unroll
    for (int t = 0; t < 8; t++) o[t] = fzero;
    float m = -1e30f, l = 0.f;

    const bf16* Kbase = Kb + (size_t)bh * S_ * HD_;
    const bf16* Vbase = Vt + (size_t)bh * HD_ * S_;

    int ksrc[4], vsrc[4];
#pragma unroll
    for (int p = 0; p < 4; p++) {
        const int g = p * 256 + tid;
        const int kr = g >> 4, kb = g & 15;
        ksrc[p] = kr * HD_ + ((kb ^ (kr & 7)) << 3);
        const int vr = g >> 3, vb = g & 7;
        vsrc[p] = vr * S_ + ((vb ^ (vr & 7)) << 3);
    }
    const int ldst = tid << 4;

    {
        const bf16* Kp = Kbase;
        const bf16* Vp = Vbase;
#pragma unroll
        for (int p = 0; p < 4; p++) {
            gload_lds(Kp + ksrc[p], Ksm[0] + p * 4096 + ldst);
            gload_lds(Vp + vsrc[p], Vsm[0] + p * 4096 + ldst);
        }
    }
    __syncthreads();

    const int nkt = qb + 1;
    for (int kt = 0; kt < nkt; kt++) {
        const int cur = kt & 1;
        const int k0 = kt << 6;

        if (kt + 1 < nkt) {
            const bf16* Kp = Kbase + (size_t)(kt + 1) * 64 * HD_;
            const bf16* Vp = Vbase + (kt + 1) * 64;
            char* Kd = Ksm[cur ^ 1];
            char* Vd = Vsm[cur ^ 1];
#pragma unroll
            for (int p = 0; p < 4; p++) {
                gload_lds(Kp + ksrc[p], Kd + p * 4096 + ldst);
                gload_lds(Vp + vsrc[p], Vd + p * 4096 + ldst);
            }
        }
        const char* Kcur = Ksm[cur];
        const char* Vcur = Vsm[cur];

        f4v sc[4];
        __builtin_amdgcn_s_setprio(1);
#pragma unroll
        for (int st = 0; st < 4; st++) {
            sc[st] = fzero;
#pragma unroll
            for (int c = 0; c < 4; c++) {
                const s8v kf = *(const s8v*)(Kcur + (st * 16 + col) * 256 +
                                             ((c * 64 + quad * 16) ^ sw));
                sc[st] = mfma16(kf, aq[c], sc[st]);
            }
        }
        __builtin_amdgcn_s_setprio(0);

        float s[16];
        float mx = -1e30f;
#pragma unroll
        for (int st = 0; st < 4; st++)
#pragma unroll
            for (int r = 0; r < 4; r++) {
                const int key = k0 + st * 16 + (quad << 2) + r;
                float v = sc[st][r] * INV_NORM + slope * (float)key;
                v = (key > qg) ? -1e9f : v;
                s[st * 4 + r] = v;
                mx = fmaxf(mx, v);
            }
        mx = fmaxf(mx, __shfl_xor(mx, 16));
        mx = fmaxf(mx, __shfl_xor(mx, 32));
        const float nm = fmaxf(m, mx);
        float ps = 0.f;
#pragma unroll
        for (int i = 0; i < 16; i++) { s[i] = __expf(s[i] - nm); ps += s[i]; }
        ps += __shfl_xor(ps, 16);
        ps += __shfl_xor(ps, 32);
        const float alpha = __expf(m - nm);
        l = l * alpha + ps;
        m = nm;
#pragma unroll
        for (int t = 0; t < 8; t++) o[t] *= alpha;

        char* plw = Pl + wave * 2048 + col * 128;
#pragma unroll
        for (int st = 0; st < 4; st++) {
            union { ushort4 u4; bf16 hh[4]; } pk;
#pragma unroll
            for (int r = 0; r < 4; r++) pk.hh[r] = __float2bfloat16(s[st * 4 + r]);
            *(ushort4*)(plw + ((st * 32 + quad * 8) ^ sw)) = pk.u4;
        }
        const s8v pf0 = *(const s8v*)(plw + ((quad * 16) ^ sw));
        const s8v pf1 = *(const s8v*)(plw + ((64 + quad * 16) ^ sw));

        __builtin_amdgcn_s_setprio(1);
#pragma unroll
        for (int t = 0; t < 8; t++) {
            const s8v vf0 = *(const s8v*)(Vcur + (t * 16 + col) * 128 +
                                          ((quad * 16) ^ sw));
            o[t] = mfma16(vf0, pf0, o[t]);
            const s8v vf1 = *(const s8v*)(Vcur + (t * 16 + col) * 128 +
                                          ((64 + quad * 16) ^ sw));
            o[t] = mfma16(vf1, pf1, o[t]);
        }
        __builtin_amdgcn_s_setprio(0);

        __syncthreads();
    }

    const float rl = 1.0f / l;
#pragma unroll
    for (int t = 0; t < 8; t++) {
        union { ushort4 u4; bf16 hh[4]; } pk;
#pragma unroll
        for (int r = 0; r < 4; r++) pk.hh[r] = __float2bfloat16(o[t][r] * rl);
        *(ushort4*)&ctx[((size_t)(b * S_) + qg) * D_ + h * HD_ + t * 16 + (quad << 2)] =
            pk.u4;
    }
}

extern "C" void kernel_launch(void* const* d_in, const int* in_sizes, int n_in,
                              void* d_out, int out_size, void* d_ws, size_t ws_size,
                              hipStream_t stream)
{
    const float* hs    = (const float*)d_in[0];
    const float* resid = (const float*)d_in[1];
    // d_in[2] = alibi: analytic (slope = 2^(-0.5*(h+1)), score += slope*key)
    // d_in[3] = attention_mask: pure causal tril/-1e9, applied analytically
    const float* Wqkv  = (const float*)d_in[4];
    const float* bqkv  = (const float*)d_in[5];
    const float* Wd    = (const float*)d_in[6];
    const float* bd    = (const float*)d_in[7];
    float* out = (float*)d_out;

    const size_t seg  = (size_t)B_ * H_ * S_ * HD_;   // 8,388,608 elems
    const size_t nHS  = (size_t)B_ * S_ * D_;         // 8,388,608
    const size_t nWq  = (size_t)3 * D_ * D_;          // 12,582,912
    const size_t nWd  = (size_t)D_ * D_;              // 4,194,304
    bf16* Qbuf = (bf16*)d_ws;
    bf16* Kbuf = Qbuf + seg;
    bf16* Vtb  = Kbuf + seg;
    bf16* ctx  = Vtb + seg;
    bf16* hsb  = ctx + seg;
    bf16* Wqb  = hsb + nHS;
    bf16* Wdb  = Wqb + nWq;          // end: 58,720,256 bf16 = 117.4 MB

    cvt_f32_bf16<<<(int)(nHS / 4 + 255) / 256, 256, 0, stream>>>(hs, hsb, (int)(nHS / 4));
    cvt_f32_bf16<<<(int)(nWq / 4 + 255) / 256, 256, 0, stream>>>(Wqkv, Wqb, (int)(nWq / 4));
    cvt_f32_bf16<<<(int)(nWd / 4 + 255) / 256, 256, 0, stream>>>(Wd, Wdb, (int)(nWd / 4));

    gemm_qkv9<<<dim3(32, 16), 512, 0, stream>>>(hsb, Wqb, bqkv, Qbuf, Kbuf, Vtb);
    attn<<<dim3(32, 32), 256, 0, stream>>>(Qbuf, Kbuf, Vtb, ctx);
    gemm_dense8<<<dim3(16, 16), 512, 0, stream>>>(ctx, Wdb, bd, resid, out);
}

// Round 10
// 390.002 us; speedup vs baseline: 1.0983x; 1.0983x over previous
//
#include <hip/hip_runtime.h>
#include <hip/hip_bf16.h>

typedef __hip_bfloat16 bf16;
typedef __attribute__((ext_vector_type(8))) short s8v;   // 8 bf16 = 4 VGPRs (MFMA A/B frag)
typedef __attribute__((ext_vector_type(4))) float f4v;   // MFMA C/D frag

#define B_  2
#define S_  2048
#define D_  2048
#define H_  16
#define HD_ 128
#define INV_NORM 0.08838834764831845f

static __device__ __forceinline__ f4v mfma16(s8v a, s8v b, f4v c) {
    return __builtin_amdgcn_mfma_f32_16x16x32_bf16(a, b, c, 0, 0, 0);
}

static __device__ __forceinline__ void gload_lds(const void* gp, void* lp) {
    __builtin_amdgcn_global_load_lds(
        (const __attribute__((address_space(1))) unsigned int*)gp,
        (__attribute__((address_space(3))) unsigned int*)lp, 16, 0, 0);
}

// fp32 -> bf16 elementwise convert, 4 elems/thread
__global__ __launch_bounds__(256)
void cvt_f32_bf16(const float* __restrict__ src, bf16* __restrict__ dst, int n4)
{
    int i = blockIdx.x * 256 + threadIdx.x;
    if (i < n4) {
        float4 f = ((const float4*)src)[i];
        union { ushort4 u4; bf16 h[4]; } p;
        p.h[0] = __float2bfloat16(f.x);
        p.h[1] = __float2bfloat16(f.y);
        p.h[2] = __float2bfloat16(f.z);
        p.h[3] = __float2bfloat16(f.w);
        ((ushort4*)dst)[i] = p.u4;
    }
}

#define VMW(s) asm volatile("s_waitcnt " s ::: "memory")
#define BARR() { __builtin_amdgcn_s_barrier(); asm volatile("" ::: "memory"); }

// ---------------------------------------------------------------------------
// gemm_qkv9 — unchanged from R9 (verified: 512 equal blocks = 2 full rounds;
// qkv no longer in top-5, <111 µs). 256M x 192N, 2-phase counted-vmcnt.
// ---------------------------------------------------------------------------
#define QSTAGE2(gptr, t, choff)                                                 \
  { const size_t co = (size_t)(t) * 64;                                         \
    gload_lds(gptr + co + srcO0, lds + ((t) & 1) * 57344 + (choff) + dst0);     \
    gload_lds(gptr + co + srcO1, lds + ((t) & 1) * 57344 + (choff) + dst1); }
#define QSTAGE3(gptr, t, choff)                                                 \
  { const size_t co = (size_t)(t) * 64;                                         \
    gload_lds(gptr + co + srcO0, lds + ((t) & 1) * 57344 + (choff) + dst0);     \
    gload_lds(gptr + co + srcO1, lds + ((t) & 1) * 57344 + (choff) + dst1);     \
    gload_lds(gptr + co + srcO2, lds + ((t) & 1) * 57344 + (choff) + dst2); }

#define QKTILE(P1, P2, VA)                                                      \
  {                                                                             \
    const int bufB = (kt & 1) * 57344;                                          \
    VMW(VA); BARR();                                                            \
    if (P1) QSTAGE2(gA2, kt + 1, 16384);                                        \
    _Pragma("unroll") for (int mi = 0; mi < 4; ++mi) {                          \
      a0[mi][0] = *(const s8v*)(lds + bufB + aR + mi * 4096 + sx0);             \
      a0[mi][1] = *(const s8v*)(lds + bufB + aR + mi * 4096 + sx1);             \
    }                                                                           \
    _Pragma("unroll") for (int nj = 0; nj < 3; ++nj) {                          \
      bfr[nj][0] = *(const s8v*)(lds + bufB + bR + nj * 2048 + sx0);            \
      bfr[nj][1] = *(const s8v*)(lds + bufB + bR + nj * 2048 + sx1);            \
    }                                                                           \
    __builtin_amdgcn_s_setprio(1);                                              \
    _Pragma("unroll") for (int mi = 0; mi < 4; ++mi)                            \
    _Pragma("unroll") for (int nj = 0; nj < 3; ++nj) {                          \
      acc[mi][nj] = mfma16(a0[mi][0], bfr[nj][0], acc[mi][nj]);                 \
      acc[mi][nj] = mfma16(a0[mi][1], bfr[nj][1], acc[mi][nj]);                 \
    }                                                                           \
    __builtin_amdgcn_s_setprio(0);                                              \
    BARR();                                                                     \
    if (P2) { QSTAGE2(gA, kt + 2, 0); QSTAGE3(gB, kt + 2, 32768); }             \
    _Pragma("unroll") for (int mi = 0; mi < 4; ++mi) {                          \
      a1[mi][0] = *(const s8v*)(lds + bufB + aR + (4 + mi) * 4096 + sx0);       \
      a1[mi][1] = *(const s8v*)(lds + bufB + aR + (4 + mi) * 4096 + sx1);       \
    }                                                                           \
    __builtin_amdgcn_s_setprio(1);                                              \
    _Pragma("unroll") for (int mi = 0; mi < 4; ++mi)                            \
    _Pragma("unroll") for (int nj = 0; nj < 3; ++nj) {                          \
      acc[4 + mi][nj] = mfma16(a1[mi][0], bfr[nj][0], acc[4 + mi][nj]);         \
      acc[4 + mi][nj] = mfma16(a1[mi][1], bfr[nj][1], acc[4 + mi][nj]);         \
    }                                                                           \
    __builtin_amdgcn_s_setprio(0);                                              \
  }

__global__ __launch_bounds__(512, 2)
void gemm_qkv9(const bf16* __restrict__ A, const bf16* __restrict__ Bw,
               const float* __restrict__ bias,
               bf16* __restrict__ o0, bf16* __restrict__ o1, bf16* __restrict__ o2)
{
    __shared__ __align__(16) char lds[114688];
    const int tid  = threadIdx.x;
    const int wave = tid >> 6, lane = tid & 63;
    const int col  = lane & 15, quad = lane >> 4;
    const int wr   = wave >> 2, wc = wave & 3;

    // XCD-chunked bijective block swizzle (nwg=512, 512%8==0):
    int id = (int)blockIdx.y * 32 + (int)blockIdx.x;
    id = (id & 7) * 64 + (id >> 3);
    const int bm = id >> 5, bn = id & 31;

    const bf16* gA  = A  + (size_t)bm * 256 * 2048;
    const bf16* gA2 = gA + (size_t)128 * 2048;
    const bf16* gB  = Bw + (size_t)bn * 192 * 2048;

    const int r0   = tid >> 3, bk0 = tid & 7;
    const int srcO0 = r0 * 2048 + ((bk0 ^ (r0 & 7)) << 3);
    const int srcO1 = srcO0 + 64 * 2048;            // rows +64 (same row&7)
    const int srcO2 = srcO0 + 128 * 2048;           // rows +128 (B only)
    const int dst0 = tid * 16, dst1 = dst0 + 8192, dst2 = dst0 + 16384;

    const int sx0 = ((quad ^ (col & 7)) << 4);          // ks=0 swizzled k-blk
    const int sx1 = (((4 + quad) ^ (col & 7)) << 4);    // ks=1
    const int aR  = (wr * 16 + col) * 128;              // + mi*4096
    const int bR  = (wc * 48 + col) * 128 + 32768;      // + nj*2048

    const f4v fzero = {0.f, 0.f, 0.f, 0.f};
    f4v acc[8][3];
#pragma unroll
    for (int i = 0; i < 8; i++)
#pragma unroll
        for (int j = 0; j < 3; j++) acc[i][j] = fzero;
    s8v a0[4][2], a1[4][2], bfr[3][2];

    // prologue: t0 {A-lo, B, A-hi} + t1 {A-lo, B} = 12 loads (FIFO)
    QSTAGE2(gA,  0, 0);
    QSTAGE3(gB,  0, 32768);
    QSTAGE2(gA2, 0, 16384);
    QSTAGE2(gA,  1, 0);
    QSTAGE3(gB,  1, 32768);

    for (int kt = 0; kt < 30; ++kt) {
        QKTILE(1, 1, "vmcnt(5)");
    }
    {   const int kt = 30;
        QKTILE(1, 0, "vmcnt(5)");
    }
    {   const int kt = 31;
        QKTILE(0, 0, "vmcnt(0)");
    }

#pragma unroll
    for (int mi = 0; mi < 8; ++mi) {
#pragma unroll
        for (int nj = 0; nj < 3; ++nj) {
            const int c  = bn * 192 + wc * 48 + nj * 16 + col;
            const int cg = c >> 7;
            const int t3 = cg % 3, hh = cg / 3;
            const int hd = c & 127;
            const float bv = bias[c];
            const int r = bm * 256 + mi * 32 + wr * 16 + (quad << 2);
            const int bi = r >> 11, srow = r & (S_ - 1);
            if (t3 == 2) {
                union { ushort4 u4; bf16 hv[4]; } pk;
#pragma unroll
                for (int rg = 0; rg < 4; ++rg)
                    pk.hv[rg] = __float2bfloat16(acc[mi][nj][rg] + bv);
                *(ushort4*)(o2 + ((size_t)(bi * H_ + hh) * HD_ + hd) * S_ + srow) = pk.u4;
            } else {
                bf16* dst = (t3 == 0) ? o0 : o1;
#pragma unroll
                for (int rg = 0; rg < 4; ++rg)
                    dst[((size_t)(bi * H_ + hh) * S_ + (srow + rg)) * HD_ + hd] =
                        __float2bfloat16(acc[mi][nj][rg] + bv);
            }
        }
    }
}

// ---------------------------------------------------------------------------
// gemm_dense8 — unchanged from R8 (verified). out = ctx @ Wd^T + bias + resid.
// ---------------------------------------------------------------------------
#define STAGE_D(gptr, t, choff)                                                 \
  { const size_t co = (size_t)(t) * 64;                                         \
    gload_lds(gptr + co + srcO0, lds + ((t) & 1) * 49152 + (choff) + dst0);     \
    gload_lds(gptr + co + srcO1, lds + ((t) & 1) * 49152 + (choff) + dst1); }

#define DKTILE(P1, P2, VA)                                                      \
  {                                                                             \
    const int bufB = (kt & 1) * 49152;                                          \
    VMW(VA); BARR();                                                            \
    if (P1) STAGE_D(gA2, kt + 1, 16384);                                        \
    _Pragma("unroll") for (int mi = 0; mi < 2; ++mi) {                          \
      alo[mi][0] = *(const s8v*)(lds + bufB + aR + mi * 8192 + sx0);            \
      alo[mi][1] = *(const s8v*)(lds + bufB + aR + mi * 8192 + sx1);            \
    }                                                                           \
    _Pragma("unroll") for (int nj = 0; nj < 4; ++nj) {                          \
      bfr[nj][0] = *(const s8v*)(lds + bufB + bR + nj * 4096 + sx0);            \
      bfr[nj][1] = *(const s8v*)(lds + bufB + bR + nj * 4096 + sx1);            \
    }                                                                           \
    __builtin_amdgcn_s_setprio(1);                                              \
    _Pragma("unroll") for (int mi = 0; mi < 2; ++mi)                            \
    _Pragma("unroll") for (int nj = 0; nj < 4; ++nj) {                          \
      acc[mi][nj] = mfma16(alo[mi][0], bfr[nj][0], acc[mi][nj]);                \
      acc[mi][nj] = mfma16(alo[mi][1], bfr[nj][1], acc[mi][nj]);                \
    }                                                                           \
    __builtin_amdgcn_s_setprio(0);                                              \
    BARR();                                                                     \
    if (P2) { STAGE_D(gA, kt + 2, 0); STAGE_D(gB, kt + 2, 32768); }             \
    _Pragma("unroll") for (int mi = 0; mi < 2; ++mi) {                          \
      ahi[mi][0] = *(const s8v*)(lds + bufB + 16384 + aR + mi * 8192 + sx0);    \
      ahi[mi][1] = *(const s8v*)(lds + bufB + 16384 + aR + mi * 8192 + sx1);    \
    }                                                                           \
    __builtin_amdgcn_s_setprio(1);                                              \
    _Pragma("unroll") for (int mi = 0; mi < 2; ++mi)                            \
    _Pragma("unroll") for (int nj = 0; nj < 4; ++nj) {                          \
      acc[2 + mi][nj] = mfma16(ahi[mi][0], bfr[nj][0], acc[2 + mi][nj]);        \
      acc[2 + mi][nj] = mfma16(ahi[mi][1], bfr[nj][1], acc[2 + mi][nj]);        \
    }                                                                           \
    __builtin_amdgcn_s_setprio(0);                                              \
  }

__global__ __launch_bounds__(512, 2)
void gemm_dense8(const bf16* __restrict__ A, const bf16* __restrict__ Bw,
                 const float* __restrict__ bias, const float* __restrict__ resid,
                 float* __restrict__ of)
{
    __shared__ __align__(16) char lds[98304];
    const int tid  = threadIdx.x;
    const int wave = tid >> 6, lane = tid & 63;
    const int col  = lane & 15, quad = lane >> 4;
    const int wr   = wave >> 1, wc = wave & 1;

    int id = (int)blockIdx.y * 16 + (int)blockIdx.x;
    id = (id & 7) * 32 + (id >> 3);
    const int bm = id >> 4, bn = id & 15;

    const bf16* gA  = A  + (size_t)bm * 256 * 2048;
    const bf16* gA2 = gA + (size_t)128 * 2048;
    const bf16* gB  = Bw + (size_t)bn * 128 * 2048;

    const int r0   = tid >> 3, bk0 = tid & 7;
    const int srcO0 = r0 * 2048 + ((bk0 ^ (r0 & 7)) << 3);
    const int srcO1 = srcO0 + 64 * 2048;
    const int dst0 = tid * 16, dst1 = dst0 + 8192;

    const int sx0 = ((quad ^ (col & 7)) << 4);
    const int sx1 = (((4 + quad) ^ (col & 7)) << 4);
    const int aR  = (wr * 16 + col) * 128;
    const int bR  = (wc * 16 + col) * 128 + 32768;

    const f4v fzero = {0.f, 0.f, 0.f, 0.f};
    f4v acc[4][4];
#pragma unroll
    for (int i = 0; i < 4; i++)
#pragma unroll
        for (int j = 0; j < 4; j++) acc[i][j] = fzero;
    s8v alo[2][2], ahi[2][2], bfr[4][2];

    STAGE_D(gA,  0, 0);
    STAGE_D(gB,  0, 32768);
    STAGE_D(gA2, 0, 16384);
    STAGE_D(gA,  1, 0);
    STAGE_D(gB,  1, 32768);

    for (int kt = 0; kt < 30; ++kt) {
        DKTILE(1, 1, "vmcnt(4)");
    }
    {   const int kt = 30;
        DKTILE(1, 0, "vmcnt(4)");
    }
    {   const int kt = 31;
        DKTILE(0, 0, "vmcnt(0)");
    }

#pragma unroll
    for (int mi = 0; mi < 4; ++mi) {
#pragma unroll
        for (int nj = 0; nj < 4; ++nj) {
            const int c = bn * 128 + nj * 32 + wc * 16 + col;
            const float bv = bias[c];
            const int r = bm * 256 + mi * 64 + wr * 16 + (quad << 2);
#pragma unroll
            for (int rg = 0; rg < 4; ++rg) {
                const size_t idx = (size_t)(r + rg) * D_ + c;
                of[idx] = acc[mi][nj][rg] + bv + resid[idx];
            }
        }
    }
}

// ---------------------------------------------------------------------------
// R10: attn retiled to 8 waves / 128 q-rows per block (R9 post-mortem: attn
// is the top kernel at 112 µs, latency-bound — MfmaUtil 12.6 / VALU 30 /
// Occ 13.4%, no pipe >40%. TLP is the deficit.)
//   - 512 thr, grid 16x32 = 512 blocks, ALL co-resident (2 blocks/CU).
//   - K/V LDS tiles shared by 2x the waves (no growth); Pl 16K -> LDS 80 KB
//     = 2 blocks/CU = 160 KB exactly -> 16 waves/CU (2x R9's 8).
//   - K/V HBM fetch amortized over 2x q-rows -> K/V traffic halves.
//   - exact per-CU balance: resident pair {id, id+256} has u=(bh>>4)&1
//     flipped -> qb = {15-x, x} -> every CU totals 34 tile-iters.
//   - uniform nkt = 2*qb+2 for all 8 waves (barrier-uniform); waves whose
//     rows end earlier see fully-masked tiles: mx=-1e9 -> nm=m, ps~0,
//     alpha=1 -> online-softmax no-op (tile 0 never fully masked -> m
//     initializes properly).
// Per-wave structure (QK^T swapped-operand, in-reg softmax reduce, Pl
// repack, PV) unchanged from the R2-verified kernel.
// ---------------------------------------------------------------------------
__global__ __launch_bounds__(512, 2)
void attn(const bf16* __restrict__ Qb, const bf16* __restrict__ Kb,
          const bf16* __restrict__ Vt, bf16* __restrict__ ctx)
{
    __shared__ __align__(16) char Ksm[2][64 * 256];     // [key][hd=128], swizzled
    __shared__ __align__(16) char Vsm[2][128 * 128];    // [hd][key=64], swizzled
    __shared__ __align__(16) char Pl[8 * 16 * 128];     // per-wave [q=16][key=64]

    const int x = blockIdx.x;                   // 0..15
    const int bh = blockIdx.y;                  // 0..31
    const int u = (bh >> 4) & 1;                // flips between id and id+256
    const int qb = u ? x : 15 - x;              // per-CU sum = 15 (exact balance)
    const int b = bh >> 4, h = bh & 15;
    const int tid = threadIdx.x;
    const int wave = tid >> 6, lane = tid & 63;
    const int col = lane & 15, quad = lane >> 4;
    const int q0 = qb << 7;                     // 128 q-rows per block
    const int qg = q0 + wave * 16 + col;        // this lane's q row (global)
    const float slope = exp2f(-0.5f * (float)(h + 1));
    const int sw = (col & 7) << 4;              // fragment-read swizzle term

    // Q fragments (B-operand): n=q=col, k=quad*8+j (+32c)
    const bf16* Qp = Qb + ((size_t)bh * S_ + q0 + wave * 16) * HD_;
    s8v aq[4];
#pragma unroll
    for (int c = 0; c < 4; c++)
        aq[c] = *(const s8v*)(Qp + (size_t)col * HD_ + c * 32 + quad * 8);

    const f4v fzero = {0.f, 0.f, 0.f, 0.f};
    f4v o[8];
#pragma unroll
    for (int t = 0; t < 8; t++) o[t] = fzero;
    float m = -1e30f, l = 0.f;

    const bf16* Kbase = Kb + (size_t)bh * S_ * HD_;
    const bf16* Vbase = Vt + (size_t)bh * HD_ * S_;

    // staging geometry: 512 thr, 2 granules each (g = p*512 + tid).
    // K tile 64x128: kr=g>>4, kb=g&15; V tile 128x64: vr=g>>3, vb=g&7.
    // Source pre-swizzled (blk ^ row&7); LDS dest linear g*16.
    int ksrc[2], vsrc[2];
#pragma unroll
    for (int p = 0; p < 2; p++) {
        const int g = p * 512 + tid;
        const int kr = g >> 4, kb = g & 15;
        ksrc[p] = kr * HD_ + ((kb ^ (kr & 7)) << 3);
        const int vr = g >> 3, vb = g & 7;
        vsrc[p] = vr * S_ + ((vb ^ (vr & 7)) << 3);
    }
    const int ldst = tid << 4;                  // + p*8192 per granule

    // prologue: DMA tile 0 into buffer 0
#pragma unroll
    for (int p = 0; p < 2; p++) {
        gload_lds(Kbase + ksrc[p], Ksm[0] + p * 8192 + ldst);
        gload_lds(Vbase + vsrc[p], Vsm[0] + p * 8192 + ldst);
    }
    __syncthreads();   // vmcnt(0) drain: tile 0 resident

    const int nkt = 2 * qb + 2;
    for (int kt = 0; kt < nkt; kt++) {
        const int cur = kt & 1;
        const int k0 = kt << 6;

        // issue next tile's DMA now; drained at this iter's end barrier.
        if (kt + 1 < nkt) {
            const bf16* Kp = Kbase + (size_t)(kt + 1) * 64 * HD_;
            const bf16* Vp = Vbase + (kt + 1) * 64;
            char* Kd = Ksm[cur ^ 1];
            char* Vd = Vsm[cur ^ 1];
#pragma unroll
            for (int p = 0; p < 2; p++) {
                gload_lds(Kp + ksrc[p], Kd + p * 8192 + ldst);
                gload_lds(Vp + vsrc[p], Vd + p * 8192 + ldst);
            }
        }
        const char* Kcur = Ksm[cur];
        const char* Vcur = Vsm[cur];

        // ---- S^T = K.Q^T : 4 sub-tiles of 16 keys ----
        f4v sc[4];
        __builtin_amdgcn_s_setprio(1);
#pragma unroll
        for (int st = 0; st < 4; st++) {
            sc[st] = fzero;
#pragma unroll
            for (int c = 0; c < 4; c++) {
                const s8v kf = *(const s8v*)(Kcur + (st * 16 + col) * 256 +
                                             ((c * 64 + quad * 16) ^ sw));
                sc[st] = mfma16(kf, aq[c], sc[st]);
            }
        }
        __builtin_amdgcn_s_setprio(0);

        // ---- scores + alibi + causal mask; per-lane = one q, 16 keys ----
        float s[16];
        float mx = -1e30f;
#pragma unroll
        for (int st = 0; st < 4; st++)
#pragma unroll
            for (int r = 0; r < 4; r++) {
                const int key = k0 + st * 16 + (quad << 2) + r;
                float v = sc[st][r] * INV_NORM + slope * (float)key;
                v = (key > qg) ? -1e9f : v;
                s[st * 4 + r] = v;
                mx = fmaxf(mx, v);
            }
        mx = fmaxf(mx, __shfl_xor(mx, 16));
        mx = fmaxf(mx, __shfl_xor(mx, 32));
        const float nm = fmaxf(m, mx);
        float ps = 0.f;
#pragma unroll
        for (int i = 0; i < 16; i++) { s[i] = __expf(s[i] - nm); ps += s[i]; }
        ps += __shfl_xor(ps, 16);
        ps += __shfl_xor(ps, 32);
        const float alpha = __expf(m - nm);
        l = l * alpha + ps;
        m = nm;
#pragma unroll
        for (int t = 0; t < 8; t++) o[t] *= alpha;

        // ---- P^T (C-layout) -> B-operand layout via per-wave LDS ----
        char* plw = Pl + wave * 2048 + col * 128;
#pragma unroll
        for (int st = 0; st < 4; st++) {
            union { ushort4 u4; bf16 hh[4]; } pk;
#pragma unroll
            for (int r = 0; r < 4; r++) pk.hh[r] = __float2bfloat16(s[st * 4 + r]);
            *(ushort4*)(plw + ((st * 32 + quad * 8) ^ sw)) = pk.u4;
        }
        const s8v pf0 = *(const s8v*)(plw + ((quad * 16) ^ sw));
        const s8v pf1 = *(const s8v*)(plw + ((64 + quad * 16) ^ sw));

        // ---- ctx^T += V^T . P^T ----
        __builtin_amdgcn_s_setprio(1);
#pragma unroll
        for (int t = 0; t < 8; t++) {
            const s8v vf0 = *(const s8v*)(Vcur + (t * 16 + col) * 128 +
                                          ((quad * 16) ^ sw));
            o[t] = mfma16(vf0, pf0, o[t]);
            const s8v vf1 = *(const s8v*)(Vcur + (t * 16 + col) * 128 +
                                          ((64 + quad * 16) ^ sw));
            o[t] = mfma16(vf1, pf1, o[t]);
        }
        __builtin_amdgcn_s_setprio(0);

        __syncthreads();   // drain next-tile DMA + protect buffers; flip
    }

    // ---- epilogue: o[t][r] = ctx^T[d=t*16+quad*4+r][q] ----
    const float rl = 1.0f / l;
#pragma unroll
    for (int t = 0; t < 8; t++) {
        union { ushort4 u4; bf16 hh[4]; } pk;
#pragma unroll
        for (int r = 0; r < 4; r++) pk.hh[r] = __float2bfloat16(o[t][r] * rl);
        *(ushort4*)&ctx[((size_t)(b * S_) + qg) * D_ + h * HD_ + t * 16 + (quad << 2)] =
            pk.u4;
    }
}

extern "C" void kernel_launch(void* const* d_in, const int* in_sizes, int n_in,
                              void* d_out, int out_size, void* d_ws, size_t ws_size,
                              hipStream_t stream)
{
    const float* hs    = (const float*)d_in[0];
    const float* resid = (const float*)d_in[1];
    // d_in[2] = alibi: analytic (slope = 2^(-0.5*(h+1)), score += slope*key)
    // d_in[3] = attention_mask: pure causal tril/-1e9, applied analytically
    const float* Wqkv  = (const float*)d_in[4];
    const float* bqkv  = (const float*)d_in[5];
    const float* Wd    = (const float*)d_in[6];
    const float* bd    = (const float*)d_in[7];
    float* out = (float*)d_out;

    const size_t seg  = (size_t)B_ * H_ * S_ * HD_;   // 8,388,608 elems
    const size_t nHS  = (size_t)B_ * S_ * D_;         // 8,388,608
    const size_t nWq  = (size_t)3 * D_ * D_;          // 12,582,912
    const size_t nWd  = (size_t)D_ * D_;              // 4,194,304
    bf16* Qbuf = (bf16*)d_ws;
    bf16* Kbuf = Qbuf + seg;
    bf16* Vtb  = Kbuf + seg;
    bf16* ctx  = Vtb + seg;
    bf16* hsb  = ctx + seg;
    bf16* Wqb  = hsb + nHS;
    bf16* Wdb  = Wqb + nWq;          // end: 58,720,256 bf16 = 117.4 MB

    cvt_f32_bf16<<<(int)(nHS / 4 + 255) / 256, 256, 0, stream>>>(hs, hsb, (int)(nHS / 4));
    cvt_f32_bf16<<<(int)(nWq / 4 + 255) / 256, 256, 0, stream>>>(Wqkv, Wqb, (int)(nWq / 4));
    cvt_f32_bf16<<<(int)(nWd / 4 + 255) / 256, 256, 0, stream>>>(Wd, Wdb, (int)(nWd / 4));

    gemm_qkv9<<<dim3(32, 16), 512, 0, stream>>>(hsb, Wqb, bqkv, Qbuf, Kbuf, Vtb);
    attn<<<dim3(16, 32), 512, 0, stream>>>(Qbuf, Kbuf, Vtb, ctx);
    gemm_dense8<<<dim3(16, 16), 512, 0, stream>>>(ctx, Wdb, bd, resid, out);
}